// Round 1
// baseline (585.913 us; speedup 1.0000x reference)
//
#include <hip/hip_runtime.h>
#include <hip/hip_fp16.h>

// One thread per row of 16 bit-floats. Pack -> fp16 add via fp32 (bit-exact,
// Figueroa: 24 >= 2*11+2) -> unpack. Memory-bound: 768 MiB total traffic.

__global__ __launch_bounds__(256) void spike_fp16_add_kernel(
    const float4* __restrict__ A, const float4* __restrict__ B,
    float4* __restrict__ O, int nrows)
{
    int i = blockIdx.x * blockDim.x + threadIdx.x;
    if (i >= nrows) return;

    const size_t base = (size_t)i * 4;  // 4 float4 per row (16 floats)

    float4 a0 = A[base + 0], a1 = A[base + 1], a2 = A[base + 2], a3 = A[base + 3];
    float4 b0 = B[base + 0], b1 = B[base + 1], b2 = B[base + 2], b3 = B[base + 3];

    // Pack MSB-first: bit j has weight 1 << (15 - j). Bits are exactly 0.0/1.0.
    uint32_t ua =
        ((uint32_t)a0.x << 15) | ((uint32_t)a0.y << 14) | ((uint32_t)a0.z << 13) | ((uint32_t)a0.w << 12) |
        ((uint32_t)a1.x << 11) | ((uint32_t)a1.y << 10) | ((uint32_t)a1.z <<  9) | ((uint32_t)a1.w <<  8) |
        ((uint32_t)a2.x <<  7) | ((uint32_t)a2.y <<  6) | ((uint32_t)a2.z <<  5) | ((uint32_t)a2.w <<  4) |
        ((uint32_t)a3.x <<  3) | ((uint32_t)a3.y <<  2) | ((uint32_t)a3.z <<  1) | ((uint32_t)a3.w);
    uint32_t ub =
        ((uint32_t)b0.x << 15) | ((uint32_t)b0.y << 14) | ((uint32_t)b0.z << 13) | ((uint32_t)b0.w << 12) |
        ((uint32_t)b1.x << 11) | ((uint32_t)b1.y << 10) | ((uint32_t)b1.z <<  9) | ((uint32_t)b1.w <<  8) |
        ((uint32_t)b2.x <<  7) | ((uint32_t)b2.y <<  6) | ((uint32_t)b2.z <<  5) | ((uint32_t)b2.w <<  4) |
        ((uint32_t)b3.x <<  3) | ((uint32_t)b3.y <<  2) | ((uint32_t)b3.z <<  1) | ((uint32_t)b3.w);

    // fp16 add via exact fp32 add + RNE convert (bit-exact vs fp16 RNE add).
    float fa = __half2float(__ushort_as_half((unsigned short)ua));
    float fb = __half2float(__ushort_as_half((unsigned short)ub));
    uint32_t us = (uint32_t)__half_as_ushort(__float2half_rn(fa + fb));

    // Unpack MSB-first.
    float4 o0, o1, o2, o3;
    o0.x = (float)((us >> 15) & 1u); o0.y = (float)((us >> 14) & 1u);
    o0.z = (float)((us >> 13) & 1u); o0.w = (float)((us >> 12) & 1u);
    o1.x = (float)((us >> 11) & 1u); o1.y = (float)((us >> 10) & 1u);
    o1.z = (float)((us >>  9) & 1u); o1.w = (float)((us >>  8) & 1u);
    o2.x = (float)((us >>  7) & 1u); o2.y = (float)((us >>  6) & 1u);
    o2.z = (float)((us >>  5) & 1u); o2.w = (float)((us >>  4) & 1u);
    o3.x = (float)((us >>  3) & 1u); o3.y = (float)((us >>  2) & 1u);
    o3.z = (float)((us >>  1) & 1u); o3.w = (float)( us         & 1u);

    O[base + 0] = o0;
    O[base + 1] = o1;
    O[base + 2] = o2;
    O[base + 3] = o3;
}

extern "C" void kernel_launch(void* const* d_in, const int* in_sizes, int n_in,
                              void* d_out, int out_size, void* d_ws, size_t ws_size,
                              hipStream_t stream) {
    const float4* A = (const float4*)d_in[0];
    const float4* B = (const float4*)d_in[1];
    float4* O = (float4*)d_out;

    int nrows = in_sizes[0] / 16;
    int block = 256;
    int grid = (nrows + block - 1) / block;
    spike_fp16_add_kernel<<<grid, block, 0, stream>>>(A, B, O, nrows);
}

// Round 2
// 577.324 us; speedup vs baseline: 1.0149x; 1.0149x over previous
//
#include <hip/hip_runtime.h>
#include <hip/hip_fp16.h>

// Fully-coalesced version: every global_load/store_dwordx4 has lane i at
// base + i*16B (1 KiB/wave/instr). Row gather/scatter done in-register:
// lane L holds quarter (L&3) of row k*16+(L>>2); nibbles are OR-combined
// across the 4-lane group via shfl_xor(1)/shfl_xor(2) (DPP quad-perm).
// All 4 lanes redundantly compute the fp16 add (VALU is ~92% idle), then
// each extracts its own quarter of the sum -> coalesced store.

__global__ __launch_bounds__(256) void spike_fp16_add_kernel(
    const float4* __restrict__ A, const float4* __restrict__ B,
    float4* __restrict__ O, int nf4)   // nf4 = total float4 count = nrows*4
{
    const int lane = threadIdx.x & 63;
    const int waveBase = ((blockIdx.x * blockDim.x + threadIdx.x) >> 6) * 256;
    const int q = lane & 3;
    const int sh = 12 - 4 * q;          // MSB-first nibble position for this quarter

    #pragma unroll
    for (int k = 0; k < 4; ++k) {
        const int f4 = waveBase + k * 64 + lane;
        if (f4 >= nf4) return;

        float4 a = A[f4];
        float4 b = B[f4];

        // pack quarter-row bits (exact 0.0/1.0 floats) into a nibble, MSB first
        uint32_t na = ((uint32_t)a.x << 3) | ((uint32_t)a.y << 2) |
                      ((uint32_t)a.z << 1) |  (uint32_t)a.w;
        uint32_t nb = ((uint32_t)b.x << 3) | ((uint32_t)b.y << 2) |
                      ((uint32_t)b.z << 1) |  (uint32_t)b.w;

        uint32_t ua = na << sh;
        uint32_t ub = nb << sh;

        // OR-combine nibbles across the 4-lane group (lanes 4m..4m+3)
        ua |= (uint32_t)__shfl_xor((int)ua, 1);
        ua |= (uint32_t)__shfl_xor((int)ua, 2);
        ub |= (uint32_t)__shfl_xor((int)ub, 1);
        ub |= (uint32_t)__shfl_xor((int)ub, 2);

        // fp16 add via exact fp32 add + RNE convert (bit-exact, Figueroa 24>=2*11+2)
        float fa = __half2float(__ushort_as_half((unsigned short)ua));
        float fb = __half2float(__ushort_as_half((unsigned short)ub));
        uint32_t us = (uint32_t)__half_as_ushort(__float2half_rn(fa + fb));

        // this lane's quarter of the sum, MSB first
        uint32_t ns = (us >> sh) & 0xFu;
        float4 o;
        o.x = (float)((ns >> 3) & 1u);
        o.y = (float)((ns >> 2) & 1u);
        o.z = (float)((ns >> 1) & 1u);
        o.w = (float)( ns       & 1u);

        O[f4] = o;
    }
}

extern "C" void kernel_launch(void* const* d_in, const int* in_sizes, int n_in,
                              void* d_out, int out_size, void* d_ws, size_t ws_size,
                              hipStream_t stream) {
    const float4* A = (const float4*)d_in[0];
    const float4* B = (const float4*)d_in[1];
    float4* O = (float4*)d_out;

    int nf4 = in_sizes[0] / 4;          // total float4s per input
    int block = 256;
    // each thread handles 4 float4s (one per k) -> threads = nf4/4
    int threads = nf4 / 4;
    int grid = (threads + block - 1) / block;
    spike_fp16_add_kernel<<<grid, block, 0, stream>>>(A, B, O, nf4);
}